// Round 1
// baseline (1497.847 us; speedup 1.0000x reference)
//
#include <hip/hip_runtime.h>
#include <hip/hip_bf16.h>

typedef unsigned short u16;
typedef __attribute__((ext_vector_type(8))) short sh8;     // 8 x bf16 (4 VGPRs)
typedef __attribute__((ext_vector_type(4))) float f32x4;   // MFMA accum

#define NV 8192
#define NG 4096
#define NE 65536

__device__ __forceinline__ u16 f2bf(float f) {
  __hip_bfloat16 h = __float2bfloat16(f);
  return __builtin_bit_cast(u16, h);
}

// ---------------- utility ----------------
__global__ void k_fill(float* __restrict__ p, float v, int n) {
  int i = blockIdx.x * 256 + threadIdx.x;
  if (i < n) p[i] = v;
}

// ---------------- Wb build: W = (d<8)?exp(-d/4):0, plus row/col sums --------
__global__ __launch_bounds__(256) void k_wb_build(
    const float* __restrict__ vert, const float* __restrict__ gpos,
    u16* __restrict__ Wb, float* __restrict__ deg_v, float* __restrict__ deg_g) {
  __shared__ float lv[192], lg[192], colp[256];
  int t = threadIdx.x;
  int v0 = blockIdx.x * 64, g0 = blockIdx.y * 64;
  if (t < 192) { lv[t] = vert[(size_t)v0 * 3 + t]; lg[t] = gpos[(size_t)g0 * 3 + t]; }
  __syncthreads();
  int w = t >> 6, lane = t & 63;
  float gx_ = lg[lane * 3], gy_ = lg[lane * 3 + 1], gz_ = lg[lane * 3 + 2];
  float csum = 0.f;
  for (int s = 0; s < 16; s++) {
    int vl = w + 4 * s;
    float dx = lv[vl * 3] - gx_, dy = lv[vl * 3 + 1] - gy_, dz = lv[vl * 3 + 2] - gz_;
    float d = sqrtf(dx * dx + dy * dy + dz * dz);
    float W = (d < 8.0f) ? expf(d * -0.25f) : 0.f;
    Wb[(size_t)(v0 + vl) * NG + g0 + lane] = f2bf(W);
    csum += W;
    float r = W;
    #pragma unroll
    for (int o = 32; o >= 1; o >>= 1) r += __shfl_xor(r, o);
    if (lane == 0) atomicAdd(&deg_v[v0 + vl], r);
  }
  colp[w * 64 + lane] = csum;
  __syncthreads();
  if (w == 0) {
    float tot = colp[lane] + colp[64 + lane] + colp[128 + lane] + colp[192 + lane];
    atomicAdd(&deg_g[g0 + lane], tot);
  }
}

__global__ void k_recip(const float* __restrict__ deg, float* __restrict__ inv,
                        float* __restrict__ rs, int n) {
  int i = blockIdx.x * 256 + threadIdx.x;
  if (i < n) { float d = deg[i]; inv[i] = 1.f / d; rs[i] = 1.f / sqrtf(d); }
}

// ---------------- edge preprocessing (CSR) ----------------
__global__ void k_edge_prep(const int* __restrict__ eidx, const float* __restrict__ ew,
                            float* __restrict__ deg_e, int* __restrict__ cnt) {
  int e = blockIdx.x * 256 + threadIdx.x;
  if (e < NE) { int d = eidx[NE + e]; atomicAdd(&deg_e[d], ew[e]); atomicAdd(&cnt[d], 1); }
}

__global__ __launch_bounds__(1024) void k_scan(const int* __restrict__ cnt,
    int* __restrict__ row_ptr, int* __restrict__ cursor) {
  __shared__ int buf0[1024], buf1[1024];
  int t = threadIdx.x;
  int b = t * 4;
  int c0 = cnt[b], c1 = cnt[b + 1], c2 = cnt[b + 2], c3 = cnt[b + 3];
  int s = c0 + c1 + c2 + c3;
  buf0[t] = s;
  __syncthreads();
  int* src = buf0; int* dst = buf1;
  for (int off = 1; off < 1024; off <<= 1) {
    int v = src[t];
    if (t >= off) v += src[t - off];
    dst[t] = v;
    __syncthreads();
    int* tmp = src; src = dst; dst = tmp;
  }
  int excl = (t == 0) ? 0 : src[t - 1];
  int r0 = excl, r1 = excl + c0, r2 = excl + c0 + c1, r3 = excl + c0 + c1 + c2;
  row_ptr[b] = r0; row_ptr[b + 1] = r1; row_ptr[b + 2] = r2; row_ptr[b + 3] = r3;
  cursor[b] = r0; cursor[b + 1] = r1; cursor[b + 2] = r2; cursor[b + 3] = r3;
  if (t == 1023) row_ptr[4096] = src[1023];
}

__global__ void k_scatter(const int* __restrict__ eidx, const float* __restrict__ ew,
                          const float* __restrict__ dinv, int* __restrict__ cursor,
                          int* __restrict__ csrc, float* __restrict__ cnorm) {
  int e = blockIdx.x * 256 + threadIdx.x;
  if (e < NE) {
    int s = eidx[e], d = eidx[NE + e];
    int slot = atomicAdd(&cursor[d], 1);
    csrc[slot] = s;
    cnorm[slot] = dinv[s] * ew[e] * dinv[d];
  }
}

// ---------------- evecs -> bf16 transposed [128][NV] ----------------
__global__ __launch_bounds__(256) void k_evecsT(const float* __restrict__ ev, u16* __restrict__ evT) {
  __shared__ float tile[32][33];
  int t = threadIdx.x;
  int v0 = blockIdx.x * 32, k0 = blockIdx.y * 32;
  int r = t >> 3, c4 = (t & 7) * 4;
  float4 x = *(const float4*)(ev + (size_t)(v0 + r) * 128 + k0 + c4);
  tile[r][c4] = x.x; tile[r][c4 + 1] = x.y; tile[r][c4 + 2] = x.z; tile[r][c4 + 3] = x.w;
  __syncthreads();
  u16* dst = evT + (size_t)(k0 + r) * NV + v0 + c4;
  dst[0] = f2bf(tile[c4][r]); dst[1] = f2bf(tile[c4 + 1][r]);
  dst[2] = f2bf(tile[c4 + 2][r]); dst[3] = f2bf(tile[c4 + 3][r]);
}

// ---------------- bf16 MFMA GEMM: C(MxN) = A(MxK) @ BT(NxK)^T ----------------
// BM=128 fixed, 4 waves in 2x2 grid, 16x16x32 MFMA, BK=32, KPAD=40.
// ATRANS: logical A[m][k] = stored[k*lda + m] (transpose-on-stage).
// AF32: A stored fp32, converted to bf16 while staging.
// grid.z = k-split slice; writes Cpart + z*M*N (reduced later).
// A2/zsplit2: slices z>=zsplit2 use A2 (for doing gradX+gradY in one launch).
template<int BN, bool AF32, bool ATRANS>
__global__ __launch_bounds__(256) void gemm_k(
    const void* __restrict__ Aptr, const void* __restrict__ A2, int zsplit2,
    const u16* __restrict__ BT, float* __restrict__ Cpart,
    int M, int N, int lda, int ldbt, int kchunk) {
  constexpr int NF = BN / 32;
  __shared__ u16 lA[128 * 40];
  __shared__ u16 lB[BN * 40];
  const int t = threadIdx.x;
  const int m0 = blockIdx.x * 128, n0 = blockIdx.y * BN;
  const void* Ause = Aptr;
  int kz = blockIdx.z;
  if (A2 != nullptr && kz >= zsplit2) { Ause = A2; kz -= zsplit2; }
  const int kbeg = kz * kchunk;
  const int lane = t & 63, wave = t >> 6;
  const int wm = (wave >> 1) * 64, wn = (wave & 1) * (BN / 2);
  f32x4 zero = {0.f, 0.f, 0.f, 0.f};
  f32x4 acc[4][NF];
  #pragma unroll
  for (int a = 0; a < 4; a++)
    #pragma unroll
    for (int b = 0; b < NF; b++) acc[a][b] = zero;

  for (int k0 = kbeg; k0 < kbeg + kchunk; k0 += 32) {
    if constexpr (!ATRANS) {
      const int r = t >> 1, cc = (t & 1) * 16;
      if constexpr (AF32) {
        const float* A = (const float*)Ause + (size_t)(m0 + r) * lda + k0 + cc;
        u16 tmp[16];
        #pragma unroll
        for (int j = 0; j < 16; j += 4) {
          float4 v = *(const float4*)(A + j);
          tmp[j] = f2bf(v.x); tmp[j + 1] = f2bf(v.y); tmp[j + 2] = f2bf(v.z); tmp[j + 3] = f2bf(v.w);
        }
        #pragma unroll
        for (int j = 0; j < 16; j++) lA[r * 40 + cc + j] = tmp[j];
      } else {
        const u16* A = (const u16*)Ause + (size_t)(m0 + r) * lda + k0 + cc;
        *(uint4*)&lA[r * 40 + cc] = *(const uint4*)A;
        *(uint4*)&lA[r * 40 + cc + 8] = *(const uint4*)(A + 8);
      }
    } else {
      const int kl = t >> 3, mb = (t & 7) * 16;
      const u16* A = (const u16*)Ause + (size_t)(k0 + kl) * lda + m0 + mb;
      u16 vals[16];
      *(uint4*)&vals[0] = *(const uint4*)A;
      *(uint4*)&vals[8] = *(const uint4*)(A + 8);
      #pragma unroll
      for (int j = 0; j < 16; j++) lA[(mb + j) * 40 + kl] = vals[j];
    }
    if constexpr (BN == 64) {
      const int r = t >> 2, cc = (t & 3) * 8;
      const u16* B = BT + (size_t)(n0 + r) * ldbt + k0 + cc;
      *(uint4*)&lB[r * 40 + cc] = *(const uint4*)B;
    } else {
      const int r = t >> 1, cc = (t & 1) * 16;
      const u16* B = BT + (size_t)(n0 + r) * ldbt + k0 + cc;
      *(uint4*)&lB[r * 40 + cc] = *(const uint4*)B;
      *(uint4*)&lB[r * 40 + cc + 8] = *(const uint4*)(B + 8);
    }
    __syncthreads();
    sh8 af[4], bfv[NF];
    #pragma unroll
    for (int mf = 0; mf < 4; mf++)
      af[mf] = *(const sh8*)&lA[(wm + mf * 16 + (lane & 15)) * 40 + (lane >> 4) * 8];
    #pragma unroll
    for (int nf = 0; nf < NF; nf++)
      bfv[nf] = *(const sh8*)&lB[(wn + nf * 16 + (lane & 15)) * 40 + (lane >> 4) * 8];
    #pragma unroll
    for (int mf = 0; mf < 4; mf++)
      #pragma unroll
      for (int nf = 0; nf < NF; nf++)
        acc[mf][nf] = __builtin_amdgcn_mfma_f32_16x16x32_bf16(af[mf], bfv[nf], acc[mf][nf], 0, 0, 0);
    __syncthreads();
  }
  float* C = Cpart + (size_t)blockIdx.z * M * N;
  #pragma unroll
  for (int mf = 0; mf < 4; mf++)
    #pragma unroll
    for (int nf = 0; nf < NF; nf++) {
      const int row = m0 + wm + mf * 16 + (lane >> 4) * 4;
      const int col = n0 + wn + nf * 16 + (lane & 15);
      #pragma unroll
      for (int q = 0; q < 4; q++)
        C[(size_t)(row + q) * N + col] = acc[mf][nf][q];
    }
}

__global__ void k_reduce(const float* __restrict__ parts, float* __restrict__ dst, int len, int nz) {
  int i = (blockIdx.x * 256 + threadIdx.x) * 4;
  if (i >= len) return;
  float4 s = *(const float4*)(parts + i);
  for (int z = 1; z < nz; z++) {
    float4 v = *(const float4*)(parts + (size_t)z * len + i);
    s.x += v.x; s.y += v.y; s.z += v.z; s.w += v.w;
  }
  *(float4*)(dst + i) = s;
}

// ---------------- small fp32 matmuls (wave-per-row, lane = out channel) -----
__global__ __launch_bounds__(256) void k_lin128(const float* __restrict__ A,
    const float* __restrict__ W, const float* __restrict__ b, float* __restrict__ out) {
  __shared__ float lW[8192];
  __shared__ float lb[64];
  int t = threadIdx.x;
  for (int i = t; i < 8192; i += 256) lW[i] = W[i];
  if (t < 64) lb[t] = b[t];
  __syncthreads();
  int row = blockIdx.x * 4 + (t >> 6), c = t & 63;
  const float* Ar = A + (size_t)row * 128;
  float acc = lb[c];
  #pragma unroll 8
  for (int k = 0; k < 128; k++) acc += Ar[k] * lW[k * 64 + c];
  out[(size_t)row * 64 + c] = acc;
}

template<bool BIAS, bool RELU, bool RES>
__global__ __launch_bounds__(256) void k_mm64(const float* __restrict__ A,
    const float* __restrict__ W, const float* __restrict__ b,
    const float* __restrict__ res, float* __restrict__ out) {
  __shared__ float lW[4096];
  __shared__ float lb[64];
  int t = threadIdx.x;
  for (int i = t; i < 4096; i += 256) lW[i] = W[i];
  if constexpr (BIAS) { if (t < 64) lb[t] = b[t]; }
  __syncthreads();
  int row = blockIdx.x * 4 + (t >> 6), c = t & 63;
  const float* Ar = A + (size_t)row * 64;
  float acc = 0.f;
  #pragma unroll 8
  for (int k = 0; k < 64; k++) acc += Ar[k] * lW[k * 64 + c];
  if constexpr (BIAS) acc += lb[c];
  if constexpr (RES) acc += res[(size_t)row * 64 + c];
  if constexpr (RELU) acc = fmaxf(acc, 0.f);
  out[(size_t)row * 64 + c] = acc;
}

template<bool TP, bool TQ>
__global__ __launch_bounds__(256) void k_mm_dual(const float* __restrict__ A,
    const float* __restrict__ W1, const float* __restrict__ W2,
    float* __restrict__ P, float* __restrict__ Q,
    u16* __restrict__ PT, u16* __restrict__ QT, int R) {
  __shared__ float l1[4096], l2[4096];
  int t = threadIdx.x;
  for (int i = t; i < 4096; i += 256) { l1[i] = W1[i]; l2[i] = W2[i]; }
  __syncthreads();
  int row = blockIdx.x * 4 + (t >> 6), c = t & 63;
  const float* Ar = A + (size_t)row * 64;
  float p = 0.f, q = 0.f;
  #pragma unroll 8
  for (int k = 0; k < 64; k++) { float a = Ar[k]; p += a * l1[k * 64 + c]; q += a * l2[k * 64 + c]; }
  P[(size_t)row * 64 + c] = p;
  Q[(size_t)row * 64 + c] = q;
  if constexpr (TP) PT[(size_t)c * R + row] = f2bf(p);
  if constexpr (TQ) QT[(size_t)c * R + row] = f2bf(q);
}

// ---------------- spectral ----------------
__global__ __launch_bounds__(64) void k_spec(const float* __restrict__ evecs,
    const float* __restrict__ mass, const float* __restrict__ dx, float* __restrict__ spec) {
  int k = blockIdx.x, c = threadIdx.x;
  int v0 = blockIdx.y * 1024;
  float a0 = 0, a1 = 0, a2 = 0, a3 = 0;
  for (int v = v0; v < v0 + 1024; v += 4) {
    a0 += evecs[(size_t)(v + 0) * 128 + k] * mass[v + 0] * dx[(size_t)(v + 0) * 64 + c];
    a1 += evecs[(size_t)(v + 1) * 128 + k] * mass[v + 1] * dx[(size_t)(v + 1) * 64 + c];
    a2 += evecs[(size_t)(v + 2) * 128 + k] * mass[v + 2] * dx[(size_t)(v + 2) * 64 + c];
    a3 += evecs[(size_t)(v + 3) * 128 + k] * mass[v + 3] * dx[(size_t)(v + 3) * 64 + c];
  }
  atomicAdd(&spec[k * 64 + c], (a0 + a1) + (a2 + a3));
}

// xd = evecs @ Es, gX = GXE @ Es, gY = GYE @ Es   (Es built in LDS)
__global__ __launch_bounds__(256) void k_xd_gxy(const float* __restrict__ evecs,
    const float* __restrict__ GXE, const float* __restrict__ GYE,
    const float* __restrict__ spec, const float* __restrict__ evals,
    const float* __restrict__ dt, float* __restrict__ xd,
    float* __restrict__ gX, float* __restrict__ gY) {
  __shared__ float lE[8192];
  int t = threadIdx.x;
  for (int i = t; i < 8192; i += 256) {
    int k = i >> 6, c = i & 63;
    float tt = fmaxf(dt[c], 1e-8f);
    lE[i] = expf(-evals[k] * tt) * spec[i];
  }
  __syncthreads();
  int row = blockIdx.x * 4 + (t >> 6), c = t & 63;
  const float* er = evecs + (size_t)row * 128;
  const float* xr = GXE + (size_t)row * 128;
  const float* yr = GYE + (size_t)row * 128;
  float a0 = 0, a1 = 0, a2 = 0;
  #pragma unroll 8
  for (int k = 0; k < 128; k++) {
    float s = lE[k * 64 + c];
    a0 += er[k] * s; a1 += xr[k] * s; a2 += yr[k] * s;
  }
  xd[(size_t)row * 64 + c] = a0;
  gX[(size_t)row * 64 + c] = a1;
  gY[(size_t)row * 64 + c] = a2;
}

__global__ __launch_bounds__(256) void k_gradfeat(const float* __restrict__ gX,
    const float* __restrict__ gY, const float* __restrict__ Are,
    const float* __restrict__ Aim, float* __restrict__ gf) {
  __shared__ float lr[4096], li[4096];
  int t = threadIdx.x;
  for (int i = t; i < 4096; i += 256) { lr[i] = Are[i]; li[i] = Aim[i]; }
  __syncthreads();
  int row = blockIdx.x * 4 + (t >> 6), c = t & 63;
  const float* xr = gX + (size_t)row * 64;
  const float* yr = gY + (size_t)row * 64;
  float br = 0.f, bi = 0.f;
  #pragma unroll 8
  for (int k = 0; k < 64; k++) {
    float xv = xr[k], yv = yr[k], ar = lr[k * 64 + c], ai = li[k * 64 + c];
    br += xv * ar - yv * ai;
    bi += yv * ar + xv * ai;
  }
  gf[(size_t)row * 64 + c] = tanhf(xr[c] * br + yr[c] * bi);
}

__global__ __launch_bounds__(256) void k_mlp0(const float* __restrict__ dx,
    const float* __restrict__ xd, const float* __restrict__ gf,
    const float* __restrict__ W0, const float* __restrict__ b0, float* __restrict__ h1) {
  __shared__ float lW[12288];
  __shared__ float lb[64];
  int t = threadIdx.x;
  for (int i = t; i < 12288; i += 256) lW[i] = W0[i];
  if (t < 64) lb[t] = b0[t];
  __syncthreads();
  int row = blockIdx.x * 4 + (t >> 6), c = t & 63;
  const float* a0 = dx + (size_t)row * 64;
  const float* a1 = xd + (size_t)row * 64;
  const float* a2 = gf + (size_t)row * 64;
  float acc = lb[c];
  #pragma unroll 8
  for (int k = 0; k < 64; k++) acc += a0[k] * lW[k * 64 + c];
  #pragma unroll 8
  for (int k = 0; k < 64; k++) acc += a1[k] * lW[(64 + k) * 64 + c];
  #pragma unroll 8
  for (int k = 0; k < 64; k++) acc += a2[k] * lW[(128 + k) * 64 + c];
  h1[(size_t)row * 64 + c] = fmaxf(acc, 0.f);
}

// ---------------- GCN aggregation (CSR gather) ----------------
template<bool RELU>
__global__ __launch_bounds__(64) void k_gcn_agg(const float* __restrict__ xw,
    const int* __restrict__ rp, const int* __restrict__ csrc,
    const float* __restrict__ cnorm, const float* __restrict__ invdeg,
    const float* __restrict__ bias, float* __restrict__ out) {
  int g = blockIdx.x, c = threadIdx.x;
  float acc = xw[(size_t)g * 64 + c] * invdeg[g] + bias[c];
  int j1 = rp[g + 1];
  for (int j = rp[g]; j < j1; j++) {
    int s = csrc[j];
    acc += cnorm[j] * xw[(size_t)s * 64 + c];
  }
  if constexpr (RELU) acc = fmaxf(acc, 0.f);
  out[(size_t)g * 64 + c] = acc;
}

// ---------------- bipartite combine ----------------
__global__ void k_combine_v(const float* __restrict__ xw_v, const float* __restrict__ Wbp,
    const float* __restrict__ xw2_v, const float* __restrict__ inv_deg_v,
    const float* __restrict__ rsv, const float* __restrict__ gsb,
    const float* __restrict__ sgb, float* __restrict__ dx) {
  int idx = blockIdx.x * 256 + threadIdx.x;
  int v = idx >> 6, c = idx & 63;
  dx[idx] = 0.5f * (xw_v[idx] * inv_deg_v[v] + Wbp[idx] * rsv[v] + gsb[c] + xw2_v[idx] + sgb[c]);
}

__global__ void k_combine_g(const float* __restrict__ xw_g, const float* __restrict__ WbTp,
    const float* __restrict__ xw2_g, const float* __restrict__ inv_deg_g,
    const float* __restrict__ rsg, const float* __restrict__ gsb,
    const float* __restrict__ sgb, float* __restrict__ gx) {
  int idx = blockIdx.x * 256 + threadIdx.x;
  int g = idx >> 6, c = idx & 63;
  gx[idx] = 0.5f * (xw_g[idx] + gsb[c] + xw2_g[idx] * inv_deg_g[g] + WbTp[idx] * rsg[g] + sgb[c]);
}

// =================================================================
extern "C" void kernel_launch(void* const* d_in, const int* in_sizes, int n_in,
                              void* d_out, int out_size, void* d_ws, size_t ws_size,
                              hipStream_t stream) {
  const float* vertices  = (const float*)d_in[0];
  const float* graph_pos = (const float*)d_in[1];
  const float* x_in      = (const float*)d_in[2];
  const float* graph_x   = (const float*)d_in[3];
  const float* mass      = (const float*)d_in[4];
  const float* evals     = (const float*)d_in[5];
  const float* evecs     = (const float*)d_in[6];
  const float* gradX     = (const float*)d_in[7];
  const float* gradY     = (const float*)d_in[8];
  const int*   eidx      = (const int*)d_in[9];
  const float* ew        = (const float*)d_in[10];
  const float* lin1_w    = (const float*)d_in[11];
  const float* lin1_b    = (const float*)d_in[12];
  const float* lin2_w    = (const float*)d_in[13];
  const float* lin2_b    = (const float*)d_in[14];
  const float* diff_time = (const float*)d_in[15];
  const float* A_re      = (const float*)d_in[16];
  const float* A_im      = (const float*)d_in[17];
  const float* mlp_w0    = (const float*)d_in[18];
  const float* mlp_b0    = (const float*)d_in[19];
  const float* mlp_w1    = (const float*)d_in[20];
  const float* mlp_b1    = (const float*)d_in[21];
  const float* mlp_w2    = (const float*)d_in[22];
  const float* mlp_b2    = (const float*)d_in[23];
  const float* gcn1_w    = (const float*)d_in[24];
  const float* gcn1_b    = (const float*)d_in[25];
  const float* gcn2_w    = (const float*)d_in[26];
  const float* gcn2_b    = (const float*)d_in[27];
  const float* gs_w      = (const float*)d_in[28];
  const float* gs_b      = (const float*)d_in[29];
  const float* sg_w      = (const float*)d_in[30];
  const float* sg_b      = (const float*)d_in[31];

  char* base = (char*)d_ws;
  size_t off = 0;
  auto alloc = [&](size_t nbytes) -> void* {
    void* p = base + off;
    off += (nbytes + 255) & ~(size_t)255;
    return p;
  };
  u16*   Wb_bf   = (u16*)alloc((size_t)NV * NG * 2);        // 64 MB
  u16*   evecsT  = (u16*)alloc((size_t)128 * NV * 2);
  float* GXE     = (float*)alloc((size_t)NV * 128 * 4);
  float* GYE     = (float*)alloc((size_t)NV * 128 * 4);
  float* parts   = (float*)alloc((size_t)4 * NV * 128 * 4); // 16 MB (max k-split use)
  float* diffx   = (float*)alloc((size_t)NV * 64 * 4);
  float* gxb     = (float*)alloc((size_t)NG * 64 * 4);
  float* spec    = (float*)alloc(8192 * 4);
  float* xd      = (float*)alloc((size_t)NV * 64 * 4);
  float* gX      = (float*)alloc((size_t)NV * 64 * 4);
  float* gY      = (float*)alloc((size_t)NV * 64 * 4);
  float* gf      = (float*)alloc((size_t)NV * 64 * 4);
  float* h1      = (float*)alloc((size_t)NV * 64 * 4);
  float* h2      = (float*)alloc((size_t)NV * 64 * 4);
  float* xw_v    = (float*)alloc((size_t)NV * 64 * 4);
  float* xw2_v   = (float*)alloc((size_t)NV * 64 * 4);
  float* xw_g    = (float*)alloc((size_t)NG * 64 * 4);
  float* xw2_g   = (float*)alloc((size_t)NG * 64 * 4);
  float* xw1     = (float*)alloc((size_t)NG * 64 * 4);
  float* gx1     = (float*)alloc((size_t)NG * 64 * 4);
  float* xw2k    = (float*)alloc((size_t)NG * 64 * 4);
  float* gx2     = (float*)alloc((size_t)NG * 64 * 4);
  u16*   xwgT    = (u16*)alloc((size_t)64 * NG * 2);
  u16*   xw2vT   = (u16*)alloc((size_t)64 * NV * 2);
  float* Wbp     = (float*)alloc((size_t)NV * 64 * 4);
  float* WbTp    = (float*)alloc((size_t)NG * 64 * 4);
  float* deg_v   = (float*)alloc(NV * 4);
  float* inv_deg_v = (float*)alloc(NV * 4);
  float* rsv     = (float*)alloc(NV * 4);
  float* deg_g   = (float*)alloc(NG * 4);
  float* inv_deg_g = (float*)alloc(NG * 4);
  float* rsg     = (float*)alloc(NG * 4);
  float* deg_e   = (float*)alloc(NG * 4);
  float* invdeg_e = (float*)alloc(NG * 4);
  float* dinv_e  = (float*)alloc(NG * 4);
  int*   cnt     = (int*)alloc(NG * 4);
  int*   row_ptr = (int*)alloc((NG + 1) * 4);
  int*   cursor  = (int*)alloc(NG * 4);
  int*   csr_src = (int*)alloc(NE * 4);
  float* csr_norm = (float*)alloc(NE * 4);
  if (off > ws_size) return;  // insufficient workspace -> fail loudly

  dim3 B256(256);

  // ---------- setup ----------
  k_fill<<<dim3(32), B256, 0, stream>>>(deg_v, 1.0f, NV);
  k_fill<<<dim3(16), B256, 0, stream>>>(deg_g, 1.0f, NG);
  k_fill<<<dim3(16), B256, 0, stream>>>(deg_e, 1.0f, NG);
  k_fill<<<dim3(16), B256, 0, stream>>>((float*)cnt, 0.0f, NG);
  k_wb_build<<<dim3(128, 64), B256, 0, stream>>>(vertices, graph_pos, Wb_bf, deg_v, deg_g);
  k_recip<<<dim3(32), B256, 0, stream>>>(deg_v, inv_deg_v, rsv, NV);
  k_recip<<<dim3(16), B256, 0, stream>>>(deg_g, inv_deg_g, rsg, NG);
  k_edge_prep<<<dim3(256), B256, 0, stream>>>(eidx, ew, deg_e, cnt);
  k_recip<<<dim3(16), B256, 0, stream>>>(deg_e, invdeg_e, dinv_e, NG);
  k_scan<<<dim3(1), dim3(1024), 0, stream>>>(cnt, row_ptr, cursor);
  k_scatter<<<dim3(256), B256, 0, stream>>>(eidx, ew, dinv_e, cursor, csr_src, csr_norm);
  k_evecsT<<<dim3(256, 4), B256, 0, stream>>>(evecs, evecsT);
  // GXE = gradX @ evecs, GYE = gradY @ evecs (once; k-split 2, z-packed)
  gemm_k<128, true, false><<<dim3(64, 1, 4), B256, 0, stream>>>(
      gradX, gradY, 2, evecsT, parts, NV, 128, NV, NV, 4096);
  k_reduce<<<dim3(1024), B256, 0, stream>>>(parts, GXE, NV * 128, 2);
  k_reduce<<<dim3(1024), B256, 0, stream>>>(parts + (size_t)2 * NV * 128, GYE, NV * 128, 2);
  k_lin128<<<dim3(2048), B256, 0, stream>>>(x_in, lin1_w, lin1_b, diffx);
  k_lin128<<<dim3(1024), B256, 0, stream>>>(graph_x, lin2_w, lin2_b, gxb);

  // ---------- 4 blocks ----------
  for (int i = 0; i < 4; i++) {
    const float* dtrow = diff_time + i * 64;
    k_fill<<<dim3(32), B256, 0, stream>>>(spec, 0.0f, 8192);
    k_spec<<<dim3(128, 8), dim3(64), 0, stream>>>(evecs, mass, diffx, spec);
    k_xd_gxy<<<dim3(2048), B256, 0, stream>>>(evecs, GXE, GYE, spec, evals, dtrow, xd, gX, gY);
    k_gradfeat<<<dim3(2048), B256, 0, stream>>>(gX, gY, A_re + i * 4096, A_im + i * 4096, gf);
    k_mlp0<<<dim3(2048), B256, 0, stream>>>(diffx, xd, gf, mlp_w0 + i * 12288, mlp_b0 + i * 64, h1);
    k_mm64<true, true, false><<<dim3(2048), B256, 0, stream>>>(h1, mlp_w1 + i * 4096, mlp_b1 + i * 64, nullptr, h2);
    k_mm64<true, false, true><<<dim3(2048), B256, 0, stream>>>(h2, mlp_w2 + i * 4096, mlp_b2 + i * 64, diffx, diffx);
    // graph GCN
    k_mm64<false, false, false><<<dim3(1024), B256, 0, stream>>>(gxb, gcn1_w + i * 4096, nullptr, nullptr, xw1);
    k_gcn_agg<true><<<dim3(NG), dim3(64), 0, stream>>>(xw1, row_ptr, csr_src, csr_norm, invdeg_e, gcn1_b + i * 64, gx1);
    k_mm64<false, false, false><<<dim3(1024), B256, 0, stream>>>(gx1, gcn2_w + i * 4096, nullptr, nullptr, xw2k);
    k_gcn_agg<false><<<dim3(NG), dim3(64), 0, stream>>>(xw2k, row_ptr, csr_src, csr_norm, invdeg_e, gcn2_b + i * 64, gx2);
    // bipartite projections
    k_mm_dual<false, true><<<dim3(2048), B256, 0, stream>>>(diffx, gs_w + i * 4096, sg_w + i * 4096,
        xw_v, xw2_v, nullptr, xw2vT, NV);
    k_mm_dual<true, false><<<dim3(1024), B256, 0, stream>>>(gx2, gs_w + i * 4096, sg_w + i * 4096,
        xw_g, xw2_g, xwgT, nullptr, NG);
    // Wbp = Wb @ xw_g  (M=NV, K=NG, ksplit 4)
    gemm_k<64, false, false><<<dim3(64, 1, 4), B256, 0, stream>>>(
        Wb_bf, nullptr, 1 << 30, xwgT, parts, NV, 64, NG, NG, 1024);
    k_reduce<<<dim3(512), B256, 0, stream>>>(parts, Wbp, NV * 64, 4);
    // WbTp = Wb^T @ xw2_v (M=NG, K=NV, ksplit 8, transpose-on-stage)
    gemm_k<64, false, true><<<dim3(32, 1, 8), B256, 0, stream>>>(
        Wb_bf, nullptr, 1 << 30, xw2vT, parts, NG, 64, NG, NV, 1024);
    k_reduce<<<dim3(256), B256, 0, stream>>>(parts, WbTp, NG * 64, 8);
    // combine
    k_combine_v<<<dim3(2048), B256, 0, stream>>>(xw_v, Wbp, xw2_v, inv_deg_v, rsv,
        gs_b + i * 64, sg_b + i * 64, diffx);
    k_combine_g<<<dim3(1024), B256, 0, stream>>>(xw_g, WbTp, xw2_g, inv_deg_g, rsg,
        gs_b + i * 64, sg_b + i * 64, gxb);
  }

  hipMemcpyAsync(d_out, diffx, (size_t)NV * 64 * 4, hipMemcpyDeviceToDevice, stream);
}

// Round 2
// 1211.869 us; speedup vs baseline: 1.2360x; 1.2360x over previous
//
#include <hip/hip_runtime.h>
#include <hip/hip_bf16.h>

typedef unsigned short u16;
typedef __attribute__((ext_vector_type(8))) short sh8;     // 8 x bf16 (4 VGPRs)
typedef __attribute__((ext_vector_type(4))) float f32x4;   // MFMA accum

#define NV 8192
#define NG 4096
#define NE 65536
#define NSLICE 32

__device__ __forceinline__ u16 f2bf(float f) {
  __hip_bfloat16 h = __float2bfloat16(f);
  return __builtin_bit_cast(u16, h);
}

// ---------------- setup fills ----------------
__global__ void k_fill4(float* __restrict__ deg_v, float* __restrict__ deg_g,
                        float* __restrict__ deg_e, int* __restrict__ cnt) {
  int i = blockIdx.x * 256 + threadIdx.x;
  if (i < NV) deg_v[i] = 1.f;
  int j = i - NV;
  if (j >= 0 && j < NG) deg_g[j] = 1.f;
  j -= NG;
  if (j >= 0 && j < NG) deg_e[j] = 1.f;
  j -= NG;
  if (j >= 0 && j < NG) cnt[j] = 0;
}

// ---------------- Wb build: W = (d<8)?exp(-d/4):0, plus row/col sums --------
__global__ __launch_bounds__(256) void k_wb_build(
    const float* __restrict__ vert, const float* __restrict__ gpos,
    u16* __restrict__ Wb, float* __restrict__ deg_v, float* __restrict__ deg_g) {
  __shared__ float lv[192], lg[192], colp[256];
  __shared__ float tile[64][65];
  int t = threadIdx.x;
  int v0 = blockIdx.x * 64, g0 = blockIdx.y * 64;
  if (t < 192) { lv[t] = vert[(size_t)v0 * 3 + t]; lg[t] = gpos[(size_t)g0 * 3 + t]; }
  __syncthreads();
  int w = t >> 6, lane = t & 63;
  float gx_ = lg[lane * 3], gy_ = lg[lane * 3 + 1], gz_ = lg[lane * 3 + 2];
  float csum = 0.f;
  #pragma unroll 4
  for (int s = 0; s < 16; s++) {
    int vl = w + 4 * s;
    float dx = lv[vl * 3] - gx_, dy = lv[vl * 3 + 1] - gy_, dz = lv[vl * 3 + 2] - gz_;
    float d = sqrtf(dx * dx + dy * dy + dz * dz);
    float W = (d < 8.0f) ? expf(d * -0.25f) : 0.f;
    Wb[(size_t)(v0 + vl) * NG + g0 + lane] = f2bf(W);
    tile[vl][lane] = W;
    csum += W;
  }
  colp[t] = csum;
  __syncthreads();
  // row sums: 4 threads per row
  int r = t >> 2, q = t & 3;
  float rs = 0.f;
  #pragma unroll
  for (int j = 0; j < 16; j++) rs += tile[r][q * 16 + j];
  rs += __shfl_xor(rs, 1);
  rs += __shfl_xor(rs, 2);
  if (q == 0) atomicAdd(&deg_v[v0 + r], rs);
  if (w == 0) {
    float tot = colp[lane] + colp[64 + lane] + colp[128 + lane] + colp[192 + lane];
    atomicAdd(&deg_g[g0 + lane], tot);
  }
}

__global__ void k_recip2(const float* __restrict__ deg_v, float* __restrict__ inv_v,
                         float* __restrict__ rs_v, const float* __restrict__ deg_g,
                         float* __restrict__ inv_g, float* __restrict__ rs_g) {
  int i = blockIdx.x * 256 + threadIdx.x;
  if (i < NV) { float d = deg_v[i]; inv_v[i] = 1.f / d; rs_v[i] = 1.f / sqrtf(d); }
  else if (i < NV + NG) {
    int j = i - NV; float d = deg_g[j]; inv_g[j] = 1.f / d; rs_g[j] = 1.f / sqrtf(d);
  }
}

__global__ void k_recip(const float* __restrict__ deg, float* __restrict__ inv,
                        float* __restrict__ rs, int n) {
  int i = blockIdx.x * 256 + threadIdx.x;
  if (i < n) { float d = deg[i]; inv[i] = 1.f / d; rs[i] = 1.f / sqrtf(d); }
}

// ---------------- edge preprocessing (CSR) ----------------
__global__ void k_edge_prep(const int* __restrict__ eidx, const float* __restrict__ ew,
                            float* __restrict__ deg_e, int* __restrict__ cnt) {
  int e = blockIdx.x * 256 + threadIdx.x;
  if (e < NE) { int d = eidx[NE + e]; atomicAdd(&deg_e[d], ew[e]); atomicAdd(&cnt[d], 1); }
}

__global__ __launch_bounds__(1024) void k_scan(const int* __restrict__ cnt,
    int* __restrict__ row_ptr, int* __restrict__ cursor) {
  __shared__ int buf0[1024], buf1[1024];
  int t = threadIdx.x;
  int b = t * 4;
  int c0 = cnt[b], c1 = cnt[b + 1], c2 = cnt[b + 2], c3 = cnt[b + 3];
  int s = c0 + c1 + c2 + c3;
  buf0[t] = s;
  __syncthreads();
  int* src = buf0; int* dst = buf1;
  for (int off = 1; off < 1024; off <<= 1) {
    int v = src[t];
    if (t >= off) v += src[t - off];
    dst[t] = v;
    __syncthreads();
    int* tmp = src; src = dst; dst = tmp;
  }
  int excl = (t == 0) ? 0 : src[t - 1];
  int r0 = excl, r1 = excl + c0, r2 = excl + c0 + c1, r3 = excl + c0 + c1 + c2;
  row_ptr[b] = r0; row_ptr[b + 1] = r1; row_ptr[b + 2] = r2; row_ptr[b + 3] = r3;
  cursor[b] = r0; cursor[b + 1] = r1; cursor[b + 2] = r2; cursor[b + 3] = r3;
  if (t == 1023) row_ptr[4096] = src[1023];
}

__global__ void k_scatter(const int* __restrict__ eidx, const float* __restrict__ ew,
                          const float* __restrict__ dinv, int* __restrict__ cursor,
                          int* __restrict__ csrc, float* __restrict__ cnorm) {
  int e = blockIdx.x * 256 + threadIdx.x;
  if (e < NE) {
    int s = eidx[e], d = eidx[NE + e];
    int slot = atomicAdd(&cursor[d], 1);
    csrc[slot] = s;
    cnorm[slot] = dinv[s] * ew[e] * dinv[d];
  }
}

// ---------------- evecs -> bf16 transposed [128][NV] ----------------
__global__ __launch_bounds__(256) void k_evecsT(const float* __restrict__ ev, u16* __restrict__ evT) {
  __shared__ float tile[32][33];
  int t = threadIdx.x;
  int v0 = blockIdx.x * 32, k0 = blockIdx.y * 32;
  int r = t >> 3, c4 = (t & 7) * 4;
  float4 x = *(const float4*)(ev + (size_t)(v0 + r) * 128 + k0 + c4);
  tile[r][c4] = x.x; tile[r][c4 + 1] = x.y; tile[r][c4 + 2] = x.z; tile[r][c4 + 3] = x.w;
  __syncthreads();
  u16* dst = evT + (size_t)(k0 + r) * NV + v0 + c4;
  dst[0] = f2bf(tile[c4][r]); dst[1] = f2bf(tile[c4 + 1][r]);
  dst[2] = f2bf(tile[c4 + 2][r]); dst[3] = f2bf(tile[c4 + 3][r]);
}

// ---------------- bf16 MFMA GEMM: C(MxN) = A(MxK) @ BT(NxK)^T ----------------
template<int BN, bool AF32, bool ATRANS>
__global__ __launch_bounds__(256) void gemm_k(
    const void* __restrict__ Aptr, const void* __restrict__ A2, int zsplit2,
    const u16* __restrict__ BT, float* __restrict__ Cpart,
    int M, int N, int lda, int ldbt, int kchunk) {
  constexpr int NF = BN / 32;
  __shared__ u16 lA[128 * 40];
  __shared__ u16 lB[BN * 40];
  const int t = threadIdx.x;
  const int m0 = blockIdx.x * 128, n0 = blockIdx.y * BN;
  const void* Ause = Aptr;
  int kz = blockIdx.z;
  if (A2 != nullptr && kz >= zsplit2) { Ause = A2; kz -= zsplit2; }
  const int kbeg = kz * kchunk;
  const int lane = t & 63, wave = t >> 6;
  const int wm = (wave >> 1) * 64, wn = (wave & 1) * (BN / 2);
  f32x4 zero = {0.f, 0.f, 0.f, 0.f};
  f32x4 acc[4][NF];
  #pragma unroll
  for (int a = 0; a < 4; a++)
    #pragma unroll
    for (int b = 0; b < NF; b++) acc[a][b] = zero;

  for (int k0 = kbeg; k0 < kbeg + kchunk; k0 += 32) {
    if constexpr (!ATRANS) {
      const int r = t >> 1, cc = (t & 1) * 16;
      if constexpr (AF32) {
        const float* A = (const float*)Ause + (size_t)(m0 + r) * lda + k0 + cc;
        u16 tmp[16];
        #pragma unroll
        for (int j = 0; j < 16; j += 4) {
          float4 v = *(const float4*)(A + j);
          tmp[j] = f2bf(v.x); tmp[j + 1] = f2bf(v.y); tmp[j + 2] = f2bf(v.z); tmp[j + 3] = f2bf(v.w);
        }
        *(uint4*)&lA[r * 40 + cc] = *(uint4*)&tmp[0];
        *(uint4*)&lA[r * 40 + cc + 8] = *(uint4*)&tmp[8];
      } else {
        const u16* A = (const u16*)Ause + (size_t)(m0 + r) * lda + k0 + cc;
        *(uint4*)&lA[r * 40 + cc] = *(const uint4*)A;
        *(uint4*)&lA[r * 40 + cc + 8] = *(const uint4*)(A + 8);
      }
    } else {
      const int kl = t >> 3, mb = (t & 7) * 16;
      const u16* A = (const u16*)Ause + (size_t)(k0 + kl) * lda + m0 + mb;
      u16 vals[16];
      *(uint4*)&vals[0] = *(const uint4*)A;
      *(uint4*)&vals[8] = *(const uint4*)(A + 8);
      #pragma unroll
      for (int j = 0; j < 16; j++) lA[(mb + j) * 40 + kl] = vals[j];
    }
    if constexpr (BN == 64) {
      const int r = t >> 2, cc = (t & 3) * 8;
      const u16* B = BT + (size_t)(n0 + r) * ldbt + k0 + cc;
      *(uint4*)&lB[r * 40 + cc] = *(const uint4*)B;
    } else {
      const int r = t >> 1, cc = (t & 1) * 16;
      const u16* B = BT + (size_t)(n0 + r) * ldbt + k0 + cc;
      *(uint4*)&lB[r * 40 + cc] = *(const uint4*)B;
      *(uint4*)&lB[r * 40 + cc + 8] = *(const uint4*)(B + 8);
    }
    __syncthreads();
    sh8 af[4], bfv[NF];
    #pragma unroll
    for (int mf = 0; mf < 4; mf++)
      af[mf] = *(const sh8*)&lA[(wm + mf * 16 + (lane & 15)) * 40 + (lane >> 4) * 8];
    #pragma unroll
    for (int nf = 0; nf < NF; nf++)
      bfv[nf] = *(const sh8*)&lB[(wn + nf * 16 + (lane & 15)) * 40 + (lane >> 4) * 8];
    #pragma unroll
    for (int mf = 0; mf < 4; mf++)
      #pragma unroll
      for (int nf = 0; nf < NF; nf++)
        acc[mf][nf] = __builtin_amdgcn_mfma_f32_16x16x32_bf16(af[mf], bfv[nf], acc[mf][nf], 0, 0, 0);
    __syncthreads();
  }
  float* C = Cpart + (size_t)blockIdx.z * M * N;
  #pragma unroll
  for (int mf = 0; mf < 4; mf++)
    #pragma unroll
    for (int nf = 0; nf < NF; nf++) {
      const int row = m0 + wm + mf * 16 + (lane >> 4) * 4;
      const int col = n0 + wn + nf * 16 + (lane & 15);
      #pragma unroll
      for (int q = 0; q < 4; q++)
        C[(size_t)(row + q) * N + col] = acc[mf][nf][q];
    }
}

__global__ void k_reduce(const float* __restrict__ parts, float* __restrict__ dst, int len, int nz) {
  int i = (blockIdx.x * 256 + threadIdx.x) * 4;
  if (i >= len) return;
  float4 s = *(const float4*)(parts + i);
  for (int z = 1; z < nz; z++) {
    float4 v = *(const float4*)(parts + (size_t)z * len + i);
    s.x += v.x; s.y += v.y; s.z += v.z; s.w += v.w;
  }
  *(float4*)(dst + i) = s;
}

// two matrices packed: dst[mat*len + j] = sum_z parts[(mat*nz+z)*len + j]
__global__ void k_reduce2(const float* __restrict__ parts, float* __restrict__ dst, int len, int nz) {
  int i = (blockIdx.x * 256 + threadIdx.x) * 4;
  if (i >= 2 * len) return;
  int mat = i / len, j = i - mat * len;
  const float* src = parts + (size_t)mat * nz * len + j;
  float4 s = *(const float4*)src;
  for (int z = 1; z < nz; z++) {
    float4 v = *(const float4*)(src + (size_t)z * len);
    s.x += v.x; s.y += v.y; s.z += v.z; s.w += v.w;
  }
  *(float4*)(dst + i) = s;
}

// ---------------- fused lin1/lin2 (C_IN=128 -> DW=64) ----------------
__global__ __launch_bounds__(256) void k_lin_both(const float* __restrict__ x_in,
    const float* __restrict__ graph_x, const float* __restrict__ W1,
    const float* __restrict__ b1, const float* __restrict__ W2,
    const float* __restrict__ b2, float* __restrict__ outV, float* __restrict__ outG) {
  __shared__ float lW[8192];
  __shared__ float lb[64];
  int bb = blockIdx.x;
  bool isV = bb < 2048;
  const float* W = isV ? W1 : W2;
  const float* bi = isV ? b1 : b2;
  const float* A = isV ? x_in : graph_x;
  float* out = isV ? outV : outG;
  int rb = isV ? bb : bb - 2048;
  int t = threadIdx.x;
  for (int i = t; i < 8192; i += 256) lW[i] = W[i];
  if (t < 64) lb[t] = bi[t];
  __syncthreads();
  int row = rb * 4 + (t >> 6), c = t & 63;
  const float* Ar = A + (size_t)row * 128;
  float acc = lb[c];
  #pragma unroll 8
  for (int k = 0; k < 128; k++) acc += Ar[k] * lW[k * 64 + c];
  out[(size_t)row * 64 + c] = acc;
}

// ---------------- spectral: sliced partial sums, no atomics ----------------
__global__ __launch_bounds__(64) void k_spec_part(const float* __restrict__ evecs,
    const float* __restrict__ mass, const float* __restrict__ dx, float* __restrict__ sp) {
  int k = blockIdx.x, c = threadIdx.x;
  int v0 = blockIdx.y * 256;
  float a0 = 0, a1 = 0, a2 = 0, a3 = 0;
  for (int v = v0; v < v0 + 256; v += 4) {
    a0 += evecs[(size_t)(v + 0) * 128 + k] * mass[v + 0] * dx[(size_t)(v + 0) * 64 + c];
    a1 += evecs[(size_t)(v + 1) * 128 + k] * mass[v + 1] * dx[(size_t)(v + 1) * 64 + c];
    a2 += evecs[(size_t)(v + 2) * 128 + k] * mass[v + 2] * dx[(size_t)(v + 2) * 64 + c];
    a3 += evecs[(size_t)(v + 3) * 128 + k] * mass[v + 3] * dx[(size_t)(v + 3) * 64 + c];
  }
  sp[(size_t)blockIdx.y * 8192 + k * 64 + c] = (a0 + a1) + (a2 + a3);
}

// Es[k][c] = exp(-evals[k]*t[c]) * sum_z sp[z][k][c]
__global__ void k_es(const float* __restrict__ sp, const float* __restrict__ evals,
                     const float* __restrict__ dt, float* __restrict__ Es) {
  int i = blockIdx.x * 256 + threadIdx.x;
  int k = i >> 6, c = i & 63;
  float s = 0.f;
  #pragma unroll 8
  for (int z = 0; z < NSLICE; z++) s += sp[(size_t)z * 8192 + i];
  Es[i] = expf(-evals[k] * fmaxf(dt[c], 1e-8f)) * s;
}

// ---------------- fused xd + gradient features ----------------
// xd = evecs@Es, gX = GXE@Es, gY = GYE@Es, gf = tanh(gX*(gX@Ar - gY@Ai) + gY*(gY@Ar + gX@Ai))
__global__ __launch_bounds__(256) void k_xdgf(const float* __restrict__ evecs,
    const float* __restrict__ GXE, const float* __restrict__ GYE,
    const float* __restrict__ Es, const float* __restrict__ Are,
    const float* __restrict__ Aim, float* __restrict__ xd, float* __restrict__ gf) {
  __shared__ float lE[8192];
  __shared__ float lr[4096], li[4096];
  __shared__ float lgx[256], lgy[256];
  int t = threadIdx.x;
  for (int i = t; i < 8192; i += 256) lE[i] = Es[i];
  for (int i = t; i < 4096; i += 256) { lr[i] = Are[i]; li[i] = Aim[i]; }
  __syncthreads();
  int wr = t >> 6, c = t & 63;
  int row = blockIdx.x * 4 + wr;
  const float* er = evecs + (size_t)row * 128;
  const float* xr = GXE + (size_t)row * 128;
  const float* yr = GYE + (size_t)row * 128;
  float a0 = 0, a1 = 0, a2 = 0;
  #pragma unroll 8
  for (int k = 0; k < 128; k++) {
    float s = lE[k * 64 + c];
    a0 += er[k] * s; a1 += xr[k] * s; a2 += yr[k] * s;
  }
  lgx[wr * 64 + c] = a1;
  lgy[wr * 64 + c] = a2;
  __syncthreads();
  float br = 0.f, bi = 0.f;
  #pragma unroll 8
  for (int k = 0; k < 64; k++) {
    float gx = lgx[wr * 64 + k], gy = lgy[wr * 64 + k];
    float ar = lr[k * 64 + c], ai = li[k * 64 + c];
    br += gx * ar - gy * ai;
    bi += gy * ar + gx * ai;
  }
  xd[(size_t)row * 64 + c] = a0;
  gf[(size_t)row * 64 + c] = tanhf(a1 * br + a2 * bi);
}

__global__ __launch_bounds__(256) void k_mlp0(const float* __restrict__ dx,
    const float* __restrict__ xd, const float* __restrict__ gf,
    const float* __restrict__ W0, const float* __restrict__ b0, float* __restrict__ h1) {
  __shared__ float lW[12288];
  __shared__ float lb[64];
  int t = threadIdx.x;
  for (int i = t; i < 12288; i += 256) lW[i] = W0[i];
  if (t < 64) lb[t] = b0[t];
  __syncthreads();
  int row = blockIdx.x * 4 + (t >> 6), c = t & 63;
  const float* a0 = dx + (size_t)row * 64;
  const float* a1 = xd + (size_t)row * 64;
  const float* a2 = gf + (size_t)row * 64;
  float acc = lb[c];
  #pragma unroll 8
  for (int k = 0; k < 64; k++) acc += a0[k] * lW[k * 64 + c];
  #pragma unroll 8
  for (int k = 0; k < 64; k++) acc += a1[k] * lW[(64 + k) * 64 + c];
  #pragma unroll 8
  for (int k = 0; k < 64; k++) acc += a2[k] * lW[(128 + k) * 64 + c];
  h1[(size_t)row * 64 + c] = fmaxf(acc, 0.f);
}

// fused mlp1 + mlp2 + residual: dx += relu(h1@W1+b1)@W2 + b2
__global__ __launch_bounds__(256) void k_mlp12(const float* __restrict__ h1,
    const float* __restrict__ W1, const float* __restrict__ b1,
    const float* __restrict__ W2, const float* __restrict__ b2, float* __restrict__ dx) {
  __shared__ float l1[4096], l2[4096], lb1[64], lb2[64], lrow[256];
  int t = threadIdx.x;
  for (int i = t; i < 4096; i += 256) { l1[i] = W1[i]; l2[i] = W2[i]; }
  if (t < 64) lb1[t] = b1[t];
  else if (t < 128) lb2[t - 64] = b2[t - 64];
  __syncthreads();
  int wr = t >> 6, c = t & 63;
  int row = blockIdx.x * 4 + wr;
  const float* hr = h1 + (size_t)row * 64;
  float h2 = lb1[c];
  #pragma unroll 8
  for (int k = 0; k < 64; k++) h2 += hr[k] * l1[k * 64 + c];
  h2 = fmaxf(h2, 0.f);
  lrow[wr * 64 + c] = h2;
  __syncthreads();
  float o = lb2[c] + dx[(size_t)row * 64 + c];
  #pragma unroll 8
  for (int k = 0; k < 64; k++) o += lrow[wr * 64 + k] * l2[k * 64 + c];
  dx[(size_t)row * 64 + c] = o;
}

// ---------------- small fp32 matmul (64x64 weights) ----------------
template<bool BIAS, bool RELU, bool RES>
__global__ __launch_bounds__(256) void k_mm64(const float* __restrict__ A,
    const float* __restrict__ W, const float* __restrict__ b,
    const float* __restrict__ res, float* __restrict__ out) {
  __shared__ float lW[4096];
  __shared__ float lb[64];
  int t = threadIdx.x;
  for (int i = t; i < 4096; i += 256) lW[i] = W[i];
  if constexpr (BIAS) { if (t < 64) lb[t] = b[t]; }
  __syncthreads();
  int row = blockIdx.x * 4 + (t >> 6), c = t & 63;
  const float* Ar = A + (size_t)row * 64;
  float acc = 0.f;
  #pragma unroll 8
  for (int k = 0; k < 64; k++) acc += Ar[k] * lW[k * 64 + c];
  if constexpr (BIAS) acc += lb[c];
  if constexpr (RES) acc += res[(size_t)row * 64 + c];
  if constexpr (RELU) acc = fmaxf(acc, 0.f);
  out[(size_t)row * 64 + c] = acc;
}

template<bool TP, bool TQ>
__global__ __launch_bounds__(256) void k_mm_dual(const float* __restrict__ A,
    const float* __restrict__ W1, const float* __restrict__ W2,
    float* __restrict__ P, float* __restrict__ Q,
    u16* __restrict__ PT, u16* __restrict__ QT, int R) {
  __shared__ float l1[4096], l2[4096];
  int t = threadIdx.x;
  for (int i = t; i < 4096; i += 256) { l1[i] = W1[i]; l2[i] = W2[i]; }
  __syncthreads();
  int row = blockIdx.x * 4 + (t >> 6), c = t & 63;
  const float* Ar = A + (size_t)row * 64;
  float p = 0.f, q = 0.f;
  #pragma unroll 8
  for (int k = 0; k < 64; k++) { float a = Ar[k]; p += a * l1[k * 64 + c]; q += a * l2[k * 64 + c]; }
  P[(size_t)row * 64 + c] = p;
  Q[(size_t)row * 64 + c] = q;
  if constexpr (TP) PT[(size_t)c * R + row] = f2bf(p);
  if constexpr (TQ) QT[(size_t)c * R + row] = f2bf(q);
}

// ---------------- GCN agg + next matmul fused ----------------
// out = [relu(agg(xw))] @ W2   (gcn1 agg -> gcn2 xw)
__global__ __launch_bounds__(64) void k_aggmm(const float* __restrict__ xw,
    const int* __restrict__ rp, const int* __restrict__ csrc,
    const float* __restrict__ cnorm, const float* __restrict__ invdeg,
    const float* __restrict__ b1, const float* __restrict__ W2, float* __restrict__ out) {
  __shared__ float lrow[64];
  int g = blockIdx.x, c = threadIdx.x;
  float acc = xw[(size_t)g * 64 + c] * invdeg[g] + b1[c];
  int j1 = rp[g + 1];
  for (int j = rp[g]; j < j1; j++) acc += cnorm[j] * xw[(size_t)csrc[j] * 64 + c];
  acc = fmaxf(acc, 0.f);
  lrow[c] = acc;
  __syncthreads();
  float o = 0.f;
  #pragma unroll 8
  for (int k = 0; k < 64; k++) o += lrow[k] * W2[k * 64 + c];
  out[(size_t)g * 64 + c] = o;
}

// gcn2 agg (+bias, no relu) -> gx2 row -> dual projection (gs_w, sg_w) + bf16 transpose of P
__global__ __launch_bounds__(64) void k_aggdual(const float* __restrict__ xw,
    const int* __restrict__ rp, const int* __restrict__ csrc,
    const float* __restrict__ cnorm, const float* __restrict__ invdeg,
    const float* __restrict__ b2, const float* __restrict__ gsw,
    const float* __restrict__ sgw, float* __restrict__ xw_g,
    float* __restrict__ xw2_g, u16* __restrict__ xwgT) {
  __shared__ float lrow[64];
  int g = blockIdx.x, c = threadIdx.x;
  float acc = xw[(size_t)g * 64 + c] * invdeg[g] + b2[c];
  int j1 = rp[g + 1];
  for (int j = rp[g]; j < j1; j++) acc += cnorm[j] * xw[(size_t)csrc[j] * 64 + c];
  lrow[c] = acc;
  __syncthreads();
  float p = 0.f, q = 0.f;
  #pragma unroll 8
  for (int k = 0; k < 64; k++) {
    float r = lrow[k];
    p += r * gsw[k * 64 + c];
    q += r * sgw[k * 64 + c];
  }
  xw_g[(size_t)g * 64 + c] = p;
  xw2_g[(size_t)g * 64 + c] = q;
  xwgT[(size_t)c * NG + g] = f2bf(p);
}

// ---------------- fused bipartite combine (vertices + graph nodes) ----------
__global__ void k_combine(const float* __restrict__ xw_v, const float* __restrict__ Wbp,
    const float* __restrict__ xw2_v, const float* __restrict__ xw_g,
    const float* __restrict__ WbTp, const float* __restrict__ xw2_g,
    const float* __restrict__ inv_deg_v, const float* __restrict__ rsv,
    const float* __restrict__ inv_deg_g, const float* __restrict__ rsg,
    const float* __restrict__ gsb, const float* __restrict__ sgb,
    float* __restrict__ dx, float* __restrict__ gx) {
  int idx = blockIdx.x * 256 + threadIdx.x;
  if (idx < NV * 64) {
    int v = idx >> 6, c = idx & 63;
    dx[idx] = 0.5f * (xw_v[idx] * inv_deg_v[v] + Wbp[idx] * rsv[v] + gsb[c] + xw2_v[idx] + sgb[c]);
  } else {
    int j = idx - NV * 64;
    int g = j >> 6, c = j & 63;
    gx[j] = 0.5f * (xw_g[j] + gsb[c] + xw2_g[j] * inv_deg_g[g] + WbTp[j] * rsg[g] + sgb[c]);
  }
}

// =================================================================
extern "C" void kernel_launch(void* const* d_in, const int* in_sizes, int n_in,
                              void* d_out, int out_size, void* d_ws, size_t ws_size,
                              hipStream_t stream) {
  const float* vertices  = (const float*)d_in[0];
  const float* graph_pos = (const float*)d_in[1];
  const float* x_in      = (const float*)d_in[2];
  const float* graph_x   = (const float*)d_in[3];
  const float* mass      = (const float*)d_in[4];
  const float* evals     = (const float*)d_in[5];
  const float* evecs     = (const float*)d_in[6];
  const float* gradX     = (const float*)d_in[7];
  const float* gradY     = (const float*)d_in[8];
  const int*   eidx      = (const int*)d_in[9];
  const float* ew        = (const float*)d_in[10];
  const float* lin1_w    = (const float*)d_in[11];
  const float* lin1_b    = (const float*)d_in[12];
  const float* lin2_w    = (const float*)d_in[13];
  const float* lin2_b    = (const float*)d_in[14];
  const float* diff_time = (const float*)d_in[15];
  const float* A_re      = (const float*)d_in[16];
  const float* A_im      = (const float*)d_in[17];
  const float* mlp_w0    = (const float*)d_in[18];
  const float* mlp_b0    = (const float*)d_in[19];
  const float* mlp_w1    = (const float*)d_in[20];
  const float* mlp_b1    = (const float*)d_in[21];
  const float* mlp_w2    = (const float*)d_in[22];
  const float* mlp_b2    = (const float*)d_in[23];
  const float* gcn1_w    = (const float*)d_in[24];
  const float* gcn1_b    = (const float*)d_in[25];
  const float* gcn2_w    = (const float*)d_in[26];
  const float* gcn2_b    = (const float*)d_in[27];
  const float* gs_w      = (const float*)d_in[28];
  const float* gs_b      = (const float*)d_in[29];
  const float* sg_w      = (const float*)d_in[30];
  const float* sg_b      = (const float*)d_in[31];

  char* base = (char*)d_ws;
  size_t off = 0;
  auto alloc = [&](size_t nbytes) -> void* {
    void* p = base + off;
    off += (nbytes + 255) & ~(size_t)255;
    return p;
  };
  u16*   Wb_bf   = (u16*)alloc((size_t)NV * NG * 2);        // 64 MB
  u16*   evecsT  = (u16*)alloc((size_t)128 * NV * 2);
  float* GXE2    = (float*)alloc((size_t)2 * NV * 128 * 4); // GXE | GYE contiguous
  float* GXE     = GXE2;
  float* GYE     = GXE2 + (size_t)NV * 128;
  float* sp      = (float*)alloc((size_t)NSLICE * 8192 * 4);
  float* Es      = (float*)alloc(8192 * 4);
  float* diffx   = (float*)alloc((size_t)NV * 64 * 4);
  float* gxb     = (float*)alloc((size_t)NG * 64 * 4);
  float* xd      = (float*)alloc((size_t)NV * 64 * 4);
  float* gf      = (float*)alloc((size_t)NV * 64 * 4);
  float* h1      = (float*)alloc((size_t)NV * 64 * 4);
  float* xw_v    = (float*)alloc((size_t)NV * 64 * 4);
  float* xw2_v   = (float*)alloc((size_t)NV * 64 * 4);
  float* xw_g    = (float*)alloc((size_t)NG * 64 * 4);
  float* xw2_g   = (float*)alloc((size_t)NG * 64 * 4);
  float* xw1     = (float*)alloc((size_t)NG * 64 * 4);
  float* xw2k    = (float*)alloc((size_t)NG * 64 * 4);
  u16*   xwgT    = (u16*)alloc((size_t)64 * NG * 2);
  u16*   xw2vT   = (u16*)alloc((size_t)64 * NV * 2);
  float* Wbp     = (float*)alloc((size_t)NV * 64 * 4);
  float* WbTp    = (float*)alloc((size_t)NG * 64 * 4);
  float* deg_v   = (float*)alloc(NV * 4);
  float* inv_deg_v = (float*)alloc(NV * 4);
  float* rsv     = (float*)alloc(NV * 4);
  float* deg_g   = (float*)alloc(NG * 4);
  float* inv_deg_g = (float*)alloc(NG * 4);
  float* rsg     = (float*)alloc(NG * 4);
  float* deg_e   = (float*)alloc(NG * 4);
  float* invdeg_e = (float*)alloc(NG * 4);
  float* dinv_e  = (float*)alloc(NG * 4);
  int*   cnt     = (int*)alloc(NG * 4);
  int*   row_ptr = (int*)alloc((NG + 1) * 4);
  int*   cursor  = (int*)alloc(NG * 4);
  int*   csr_src = (int*)alloc(NE * 4);
  float* csr_norm = (float*)alloc(NE * 4);
  // parts LAST; choose setup k-split by available workspace
  size_t bigBytes = (size_t)16 * NV * 128 * 4;   // 64 MB
  size_t smallBytes = (size_t)4 * NV * 128 * 4;  // 16 MB
  bool big = (off + bigBytes + 256 <= ws_size);
  int nzHalf = big ? 8 : 2;                      // z-slices per matrix
  float* parts = (float*)alloc(big ? bigBytes : smallBytes);
  if (off > ws_size) return;  // insufficient workspace -> fail loudly

  dim3 B256(256);

  // ---------- setup ----------
  k_fill4<<<dim3(80), B256, 0, stream>>>(deg_v, deg_g, deg_e, cnt);
  k_wb_build<<<dim3(128, 64), B256, 0, stream>>>(vertices, graph_pos, Wb_bf, deg_v, deg_g);
  k_recip2<<<dim3(48), B256, 0, stream>>>(deg_v, inv_deg_v, rsv, deg_g, inv_deg_g, rsg);
  k_edge_prep<<<dim3(256), B256, 0, stream>>>(eidx, ew, deg_e, cnt);
  k_recip<<<dim3(16), B256, 0, stream>>>(deg_e, invdeg_e, dinv_e, NG);
  k_scan<<<dim3(1), dim3(1024), 0, stream>>>(cnt, row_ptr, cursor);
  k_scatter<<<dim3(256), B256, 0, stream>>>(eidx, ew, dinv_e, cursor, csr_src, csr_norm);
  k_evecsT<<<dim3(256, 4), B256, 0, stream>>>(evecs, evecsT);
  // GXE = gradX @ evecs, GYE = gradY @ evecs (z-packed, k-split nzHalf each)
  gemm_k<128, true, false><<<dim3(64, 1, 2 * nzHalf), B256, 0, stream>>>(
      gradX, gradY, nzHalf, evecsT, parts, NV, 128, NV, NV, 8192 / nzHalf);
  k_reduce2<<<dim3(2048), B256, 0, stream>>>(parts, GXE2, NV * 128, nzHalf);
  k_lin_both<<<dim3(3072), B256, 0, stream>>>(x_in, graph_x, lin1_w, lin1_b, lin2_w, lin2_b, diffx, gxb);

  // ---------- 4 blocks ----------
  for (int i = 0; i < 4; i++) {
    const float* dtrow = diff_time + i * 64;
    k_spec_part<<<dim3(128, NSLICE), dim3(64), 0, stream>>>(evecs, mass, diffx, sp);
    k_es<<<dim3(32), B256, 0, stream>>>(sp, evals, dtrow, Es);
    k_xdgf<<<dim3(2048), B256, 0, stream>>>(evecs, GXE, GYE, Es, A_re + i * 4096, A_im + i * 4096, xd, gf);
    k_mlp0<<<dim3(2048), B256, 0, stream>>>(diffx, xd, gf, mlp_w0 + i * 12288, mlp_b0 + i * 64, h1);
    k_mlp12<<<dim3(2048), B256, 0, stream>>>(h1, mlp_w1 + i * 4096, mlp_b1 + i * 64,
        mlp_w2 + i * 4096, mlp_b2 + i * 64, diffx);
    // graph GCN (2 convs) + graph-side dual projection
    k_mm64<false, false, false><<<dim3(1024), B256, 0, stream>>>(gxb, gcn1_w + i * 4096, nullptr, nullptr, xw1);
    k_aggmm<<<dim3(NG), dim3(64), 0, stream>>>(xw1, row_ptr, csr_src, csr_norm, invdeg_e,
        gcn1_b + i * 64, gcn2_w + i * 4096, xw2k);
    k_aggdual<<<dim3(NG), dim3(64), 0, stream>>>(xw2k, row_ptr, csr_src, csr_norm, invdeg_e,
        gcn2_b + i * 64, gs_w + i * 4096, sg_w + i * 4096, xw_g, xw2_g, xwgT);
    // vertex-side dual projection
    k_mm_dual<false, true><<<dim3(2048), B256, 0, stream>>>(diffx, gs_w + i * 4096, sg_w + i * 4096,
        xw_v, xw2_v, nullptr, xw2vT, NV);
    // Wbp = Wb @ xw_g  (M=NV, K=NG, ksplit 8)
    gemm_k<64, false, false><<<dim3(64, 1, 8), B256, 0, stream>>>(
        Wb_bf, nullptr, 1 << 30, xwgT, parts, NV, 64, NG, NG, 512);
    k_reduce<<<dim3(512), B256, 0, stream>>>(parts, Wbp, NV * 64, 8);
    // WbTp = Wb^T @ xw2_v (M=NG, K=NV, ksplit 16, transpose-on-stage)
    gemm_k<64, false, true><<<dim3(32, 1, 16), B256, 0, stream>>>(
        Wb_bf, nullptr, 1 << 30, xw2vT, parts, NG, 64, NG, NV, 512);
    k_reduce<<<dim3(256), B256, 0, stream>>>(parts, WbTp, NG * 64, 16);
    // fused combine
    k_combine<<<dim3(3072), B256, 0, stream>>>(xw_v, Wbp, xw2_v, xw_g, WbTp, xw2_g,
        inv_deg_v, rsv, inv_deg_g, rsg, gs_b + i * 64, sg_b + i * 64, diffx, gxb);
  }

  hipMemcpyAsync(d_out, diffx, (size_t)NV * 64 * 4, hipMemcpyDeviceToDevice, stream);
}